// Round 5
// baseline (69.087 us; speedup 1.0000x reference)
//
#include <hip/hip_runtime.h>
#include <hip/hip_cooperative_groups.h>
#include <math.h>

namespace cg = cooperative_groups;

// CumulativeLayerNorm [B=8, K=8000, H=512] f32.
// out[b,k,h] = gamma[h]*(x[b,k,h]-mean[b,k])*rsqrt(var[b,k]+1e-8)+beta[h],
// mean/var over prefix inputs[b,:k+1,:].
//
// Primary: ONE cooperative kernel, 1000 blocks x 64 frames.
//   phase A: stream 64 frames (sum/sumsq); keep 16 frames in LDS + 24 in regs
//   grid.sync()
//   phase B: wave0 sums <=124 predecessor segment aggregates (L2 broadcast)
//            + 64-lane shuffle scan -> per-frame mean/istd in LDS
//   phase C: normalize; 40/64 frames from on-chip, 24 re-read; NT stores
// HBM traffic ~315 MB (vs 393 MB for the 4-kernel pipeline).
// Fallback (occupancy/geometry mismatch): the proven R4 4-kernel pipeline.

#define HDIM 512
#define F4H (HDIM / 4)        // 128
#define BATCHES 8
#define KLEN 8000
#define FPB 64                // frames per block (coop)
#define SEGS (KLEN / FPB)     // 125
#define NBLK (BATCHES * SEGS) // 1000
#define SEG 64                // fallback segment size

typedef float f32x4 __attribute__((ext_vector_type(4)));
typedef unsigned long long u64;

// ===================== primary: cooperative fused kernel =================
__global__ __launch_bounds__(256, 4) void cln_coop(
    const float* __restrict__ in, const float* __restrict__ gamma,
    const float* __restrict__ beta, float* __restrict__ out,
    double* __restrict__ segS, double* __restrict__ segQ)
{
    __shared__ float4 xs[16][F4H];     // 16 LDS-cached frames (32 KB)
    __shared__ float4 gb4[256];        // gamma | beta (4 KB)
    __shared__ float fsum[FPB], fsq[FPB], meanS[FPB], istdS[FPB];
    __shared__ double wS[4], wQ[4];

    const int tid  = threadIdx.x;
    const int lane = tid & 63;
    const int wid  = tid >> 6;
    const int bx   = blockIdx.x;
    const int b    = bx / SEGS;
    const int s    = bx % SEGS;

    // stage gamma/beta -> LDS (512 floats each)
    if (tid < 128) gb4[tid] = ((const float4*)gamma)[tid];
    else           gb4[tid] = ((const float4*)beta)[tid - 128];

    // this wave's 16 frames start here (float4 units)
    const size_t rowBase = ((size_t)b * KLEN + (size_t)s * FPB + wid * 16) * F4H;
    const float4* p = (const float4*)in + rowBase;

    // ---- phase A: sums; cache frames 0-3 in LDS, 4-9+... 4-9 in regs ----
    float4 rA[6], rB[6];               // 6 frames/wave in regs (48 VGPR)
    double accS = 0.0, accQ = 0.0;
    #pragma unroll
    for (int fi = 0; fi < 16; ++fi) {
        float4 a = p[(size_t)fi * F4H + lane];
        float4 c = p[(size_t)fi * F4H + 64 + lane];
        float sv = (a.x + a.y) + (a.z + a.w) + (c.x + c.y) + (c.z + c.w);
        float qv = (a.x * a.x + a.y * a.y) + (a.z * a.z + a.w * a.w)
                 + (c.x * c.x + c.y * c.y) + (c.z * c.z + c.w * c.w);
        #pragma unroll
        for (int off = 32; off >= 1; off >>= 1) {
            sv += __shfl_xor(sv, off);
            qv += __shfl_xor(qv, off);
        }
        if (lane == 0) { fsum[wid * 16 + fi] = sv; fsq[wid * 16 + fi] = qv; }
        accS += (double)sv;            // wave-uniform
        accQ += (double)qv;
        if (fi < 4)       { xs[wid * 4 + fi][lane] = a; xs[wid * 4 + fi][64 + lane] = c; }
        else if (fi < 10) { rA[fi - 4] = a; rB[fi - 4] = c; }
        // fi 10..15: streamed, re-read in phase C
    }
    if (lane == 0) { wS[wid] = accS; wQ[wid] = accQ; }
    __syncthreads();
    if (tid == 0) {
        double S = wS[0] + wS[1] + wS[2] + wS[3];
        double Q = wQ[0] + wQ[1] + wQ[2] + wQ[3];
        __hip_atomic_store((u64*)&segS[bx], __double_as_longlong(S),
                           __ATOMIC_RELEASE, __HIP_MEMORY_SCOPE_AGENT);
        __hip_atomic_store((u64*)&segQ[bx], __double_as_longlong(Q),
                           __ATOMIC_RELEASE, __HIP_MEMORY_SCOPE_AGENT);
    }

    cg::this_grid().sync();

    // ---- phase B (wave 0): exclusive prefix + intra-segment scan --------
    if (wid == 0) {
        double es = 0.0, eq = 0.0;
        for (int base = 0; base < s; base += 64) {
            const int j = base + lane;
            double a = 0.0, q2 = 0.0;
            if (j < s) {
                a  = __longlong_as_double(__hip_atomic_load((u64*)&segS[b * SEGS + j],
                        __ATOMIC_ACQUIRE, __HIP_MEMORY_SCOPE_AGENT));
                q2 = __longlong_as_double(__hip_atomic_load((u64*)&segQ[b * SEGS + j],
                        __ATOMIC_ACQUIRE, __HIP_MEMORY_SCOPE_AGENT));
            }
            es += a; eq += q2;
        }
        #pragma unroll
        for (int off = 32; off >= 1; off >>= 1) {
            es += __shfl_xor(es, off);
            eq += __shfl_xor(eq, off);
        }
        // inclusive scan over the block's 64 per-frame sums (lane = frame)
        double sc = (double)fsum[lane], qc = (double)fsq[lane];
        #pragma unroll
        for (int off = 1; off < 64; off <<= 1) {
            double s2 = __shfl_up(sc, off);
            double q2 = __shfl_up(qc, off);
            if (lane >= off) { sc += s2; qc += q2; }
        }
        sc += es; qc += eq;
        const double cnt = (double)(s * FPB + lane + 1) * (double)HDIM;
        const double m   = sc / cnt;
        const double var = qc / cnt - m * m;
        meanS[lane] = (float)m;
        istdS[lane] = (float)(1.0 / sqrt(var + 1e-8));
    }
    __syncthreads();

    // ---- phase C: normalize (streamed frames first -> best L3 odds) -----
    const float4 g0  = gb4[lane],       g1  = gb4[64 + lane];
    const float4 be0 = gb4[128 + lane], be1 = gb4[192 + lane];
    f32x4* o4 = (f32x4*)out + rowBase;

#define APPLY(fi, a, c) {                                                   \
        const float m = meanS[wid * 16 + (fi)];                             \
        const float r = istdS[wid * 16 + (fi)];                             \
        f32x4 o0, o1;                                                       \
        o0.x = g0.x * ((a.x - m) * r) + be0.x;                              \
        o0.y = g0.y * ((a.y - m) * r) + be0.y;                              \
        o0.z = g0.z * ((a.z - m) * r) + be0.z;                              \
        o0.w = g0.w * ((a.w - m) * r) + be0.w;                              \
        o1.x = g1.x * ((c.x - m) * r) + be1.x;                              \
        o1.y = g1.y * ((c.y - m) * r) + be1.y;                              \
        o1.z = g1.z * ((c.z - m) * r) + be1.z;                              \
        o1.w = g1.w * ((c.w - m) * r) + be1.w;                              \
        __builtin_nontemporal_store(o0, o4 + (size_t)(fi) * F4H + lane);    \
        __builtin_nontemporal_store(o1, o4 + (size_t)(fi) * F4H + 64 + lane); }

    #pragma unroll
    for (int fi = 10; fi < 16; ++fi) {        // re-read from global
        float4 a = p[(size_t)fi * F4H + lane];
        float4 c = p[(size_t)fi * F4H + 64 + lane];
        APPLY(fi, a, c);
    }
    #pragma unroll
    for (int fi = 4; fi < 10; ++fi) {          // from registers
        APPLY(fi, rA[fi - 4], rB[fi - 4]);
    }
    #pragma unroll
    for (int fi = 0; fi < 4; ++fi) {           // from LDS
        float4 a = xs[wid * 4 + fi][lane];
        float4 c = xs[wid * 4 + fi][64 + lane];
        APPLY(fi, a, c);
    }
#undef APPLY
}

// ===================== fallback: proven 4-kernel pipeline ================
__global__ __launch_bounds__(256) void k_seg_sums(
    const float* __restrict__ in, float* __restrict__ ssum,
    float* __restrict__ ssq, double* __restrict__ segS,
    double* __restrict__ segQ, int K, int segsPerBatch)
{
    const int lane = threadIdx.x & 63;
    const int wid  = threadIdx.x >> 6;
    const int segGlobal = blockIdx.x;
    const int b   = segGlobal / segsPerBatch;
    const int seg = segGlobal % segsPerBatch;
    const int k0  = seg * SEG;

    double accS = 0.0, accQ = 0.0;
    #pragma unroll 4
    for (int i = 0; i < SEG / 4; ++i) {
        const int fk = k0 + wid * (SEG / 4) + i;
        if (fk < K) {
            const float4* p = (const float4*)in + ((size_t)b * K + fk) * F4H;
            float4 a = p[lane];
            float4 c = p[lane + 64];
            float s = (a.x + a.y) + (a.z + a.w) + (c.x + c.y) + (c.z + c.w);
            float q = (a.x * a.x + a.y * a.y) + (a.z * a.z + a.w * a.w)
                    + (c.x * c.x + c.y * c.y) + (c.z * c.z + c.w * c.w);
            #pragma unroll
            for (int off = 32; off >= 1; off >>= 1) {
                s += __shfl_xor(s, off);
                q += __shfl_xor(q, off);
            }
            if (lane == 0) {
                ssum[(size_t)b * K + fk] = s;
                ssq[(size_t)b * K + fk]  = q;
            }
            accS += (double)s;
            accQ += (double)q;
        }
    }
    __shared__ double wS[4], wQ[4];
    if (lane == 0) { wS[wid] = accS; wQ[wid] = accQ; }
    __syncthreads();
    if (threadIdx.x == 0) {
        segS[segGlobal] = wS[0] + wS[1] + wS[2] + wS[3];
        segQ[segGlobal] = wQ[0] + wQ[1] + wQ[2] + wQ[3];
    }
}

__global__ __launch_bounds__(512) void k_seg_scan(
    const double* __restrict__ segS, const double* __restrict__ segQ,
    double* __restrict__ offS, double* __restrict__ offQ, int segsPerBatch)
{
    const int lane = threadIdx.x & 63;
    const int b = threadIdx.x >> 6;
    if (b >= BATCHES) return;

    double carryS = 0.0, carryQ = 0.0;
    for (int base = 0; base < segsPerBatch; base += 64) {
        const int sidx = base + lane;
        const bool v = sidx < segsPerBatch;
        double s = v ? segS[(size_t)b * segsPerBatch + sidx] : 0.0;
        double q = v ? segQ[(size_t)b * segsPerBatch + sidx] : 0.0;
        const double sIn = s, qIn = q;
        #pragma unroll
        for (int off = 1; off < 64; off <<= 1) {
            double s2 = __shfl_up(s, off);
            double q2 = __shfl_up(q, off);
            if (lane >= off) { s += s2; q += q2; }
        }
        if (v) {
            offS[(size_t)b * segsPerBatch + sidx] = carryS + s - sIn;
            offQ[(size_t)b * segsPerBatch + sidx] = carryQ + q - qIn;
        }
        carryS += __shfl(s, 63);
        carryQ += __shfl(q, 63);
    }
}

__global__ __launch_bounds__(256) void k_frame_stats(
    const float* __restrict__ ssum, const float* __restrict__ ssq,
    const double* __restrict__ offS, const double* __restrict__ offQ,
    float* __restrict__ mean, float* __restrict__ istd,
    int K, int segsPerBatch)
{
    const int lane = threadIdx.x & 63;
    const int segGlobal = blockIdx.x * 4 + (threadIdx.x >> 6);
    if (segGlobal >= BATCHES * segsPerBatch) return;
    const int b   = segGlobal / segsPerBatch;
    const int seg = segGlobal % segsPerBatch;
    const int k   = seg * SEG + lane;

    double s = 0.0, q = 0.0;
    if (k < K) {
        s = (double)ssum[(size_t)b * K + k];
        q = (double)ssq[(size_t)b * K + k];
    }
    #pragma unroll
    for (int off = 1; off < 64; off <<= 1) {
        double s2 = __shfl_up(s, off);
        double q2 = __shfl_up(q, off);
        if (lane >= off) { s += s2; q += q2; }
    }
    if (k < K) {
        s += offS[segGlobal];
        q += offQ[segGlobal];
        const double cnt = (double)(k + 1) * (double)HDIM;
        const double m = s / cnt;
        const double var = q / cnt - m * m;
        mean[(size_t)b * K + k] = (float)m;
        istd[(size_t)b * K + k] = (float)(1.0 / sqrt(var + 1e-8));
    }
}

__global__ __launch_bounds__(256) void k_normalize(
    const float* __restrict__ in, const float* __restrict__ gamma,
    const float* __restrict__ beta, const float* __restrict__ mean,
    const float* __restrict__ istd, float* __restrict__ out, int nframes)
{
    const int t = threadIdx.x;
    const int frame = blockIdx.x * 2 + (t >> 7);
    const int c = t & (F4H - 1);
    if (frame >= nframes) return;

    const float m = mean[frame];
    const float r = istd[frame];
    const float4 g  = ((const float4*)gamma)[c];
    const float4 be = ((const float4*)beta)[c];
    const float4 x  = ((const float4*)in)[(size_t)frame * F4H + c];

    f32x4 o;
    o.x = g.x * ((x.x - m) * r) + be.x;
    o.y = g.y * ((x.y - m) * r) + be.y;
    o.z = g.z * ((x.z - m) * r) + be.z;
    o.w = g.w * ((x.w - m) * r) + be.w;
    __builtin_nontemporal_store(o, (f32x4*)out + (size_t)frame * F4H + c);
}

// =========================== host launcher ===============================
extern "C" void kernel_launch(void* const* d_in, const int* in_sizes, int n_in,
                              void* d_out, int out_size, void* d_ws, size_t ws_size,
                              hipStream_t stream)
{
    const float* in    = (const float*)d_in[0];
    const float* gamma = (const float*)d_in[1];
    const float* beta  = (const float*)d_in[2];
    float* out = (float*)d_out;

    const int H  = in_sizes[1];
    const int BK = in_sizes[0] / H;
    const int K  = BK / BATCHES;
    (void)n_in; (void)out_size; (void)ws_size;

    // ws: segS/segQ f64 [NBLK] (coop), then fallback arrays
    double* segS = (double*)d_ws;
    double* segQ = segS + NBLK;
    float* ssum = (float*)(segQ + NBLK);
    float* ssq  = ssum + BK;
    float* mean = ssq + BK;
    float* istd = mean + BK;
    double* fsegS = (double*)(istd + BK);
    double* fsegQ = fsegS + BATCHES * ((K + SEG - 1) / SEG);
    double* offS  = fsegQ + BATCHES * ((K + SEG - 1) / SEG);
    double* offQ  = offS  + BATCHES * ((K + SEG - 1) / SEG);

    // geometry + co-residency check for the cooperative path (deterministic
    // per device: same inputs -> same path every call)
    bool coop = (H == HDIM) && (K == KLEN) && (in_sizes[0] == BATCHES * KLEN * HDIM);
    if (coop) {
        int dev = 0, nb = 0, cus = 0;
        if (hipGetDevice(&dev) != hipSuccess) coop = false;
        if (coop && hipOccupancyMaxActiveBlocksPerMultiprocessor(
                        &nb, (const void*)cln_coop, 256, 0) != hipSuccess) coop = false;
        if (coop && hipDeviceGetAttribute(&cus, hipDeviceAttributeMultiprocessorCount,
                                          dev) != hipSuccess) coop = false;
        if (coop && (long)nb * cus < NBLK) coop = false;
    }

    if (coop) {
        void* args[] = {(void*)&in, (void*)&gamma, (void*)&beta,
                        (void*)&out, (void*)&segS, (void*)&segQ};
        hipLaunchCooperativeKernel((const void*)cln_coop, dim3(NBLK), dim3(256),
                                   args, 0, stream);
    } else {
        const int segsPerBatch = (K + SEG - 1) / SEG;
        const int NSEG = BATCHES * segsPerBatch;
        k_seg_sums<<<dim3(NSEG), dim3(256), 0, stream>>>(
            in, ssum, ssq, fsegS, fsegQ, K, segsPerBatch);
        k_seg_scan<<<dim3(1), dim3(512), 0, stream>>>(
            fsegS, fsegQ, offS, offQ, segsPerBatch);
        k_frame_stats<<<dim3((NSEG + 3) / 4), dim3(256), 0, stream>>>(
            ssum, ssq, offS, offQ, mean, istd, K, segsPerBatch);
        k_normalize<<<dim3((BK + 1) / 2), dim3(256), 0, stream>>>(
            in, gamma, beta, mean, istd, out, BK);
    }
}

// Round 6
// 69.017 us; speedup vs baseline: 1.0010x; 1.0010x over previous
//
#include <hip/hip_runtime.h>
#include <hip/hip_cooperative_groups.h>
#include <math.h>

namespace cg = cooperative_groups;

// CumulativeLayerNorm [B=8, K=8000, H=512] f32.
// out[b,k,h] = gamma[h]*(x[b,k,h]-mean[b,k])*rsqrt(var[b,k]+1e-8)+beta[h],
// mean/var over prefix inputs[b,:k+1,:].
//
// Primary: ONE cooperative kernel, 1000 blocks x 256 threads, 64 frames/block,
// 16 frames/wave held ENTIRELY in registers (128 VGPR) across the grid sync.
//   phase A: load 16 frames -> regs, per-frame sum/sumsq, segment aggregate
//   grid.sync()
//   phase B: wave0: sum <=124 predecessor aggregates + 64-lane shuffle scan
//            -> per-frame mean/istd in LDS
//   phase C: normalize straight from registers; NT stores. ZERO re-read.
// HBM traffic = 131 read + 131 write = 262 MB (the floor).
// Fallback (occupancy/geometry mismatch): proven R4 4-kernel pipeline.

#define HDIM 512
#define F4H (HDIM / 4)        // 128
#define BATCHES 8
#define KLEN 8000
#define FPB 64                // frames per block (coop)
#define SEGS (KLEN / FPB)     // 125
#define NBLK (BATCHES * SEGS) // 1000
#define SEG 64                // fallback segment size

typedef float f32x4 __attribute__((ext_vector_type(4)));
typedef unsigned long long u64;

// ===================== primary: cooperative fused kernel =================
__global__ __launch_bounds__(256, 4) void cln_coop(
    const float* __restrict__ in, const float* __restrict__ gamma,
    const float* __restrict__ beta, float* __restrict__ out,
    double* __restrict__ segS, double* __restrict__ segQ)
{
    __shared__ float fsum[FPB], fsq[FPB], meanS[FPB], istdS[FPB];
    __shared__ double wS[4], wQ[4];

    const int tid  = threadIdx.x;
    const int lane = tid & 63;
    const int wid  = tid >> 6;
    const int bx   = blockIdx.x;
    const int b    = bx / SEGS;
    const int s    = bx % SEGS;

    // gamma/beta for this lane's columns, held in regs across the sync
    const f32x4 g0  = ((const f32x4*)gamma)[lane];
    const f32x4 g1  = ((const f32x4*)gamma)[lane + 64];
    const f32x4 be0 = ((const f32x4*)beta)[lane];
    const f32x4 be1 = ((const f32x4*)beta)[lane + 64];

    // this wave's 16 frames (float4 units)
    const size_t rowBase = ((size_t)b * KLEN + (size_t)s * FPB + wid * 16) * F4H;
    const f32x4* p = (const f32x4*)in + rowBase;

    // ---- phase A: load all 16 frames into registers, then reduce --------
    f32x4 xa[16], xc[16];              // 128 VGPR, statically indexed
    #pragma unroll
    for (int fi = 0; fi < 16; ++fi) {
        xa[fi] = p[(size_t)fi * F4H + lane];
        xc[fi] = p[(size_t)fi * F4H + 64 + lane];
    }
    double accS = 0.0, accQ = 0.0;
    #pragma unroll
    for (int fi = 0; fi < 16; ++fi) {
        float sv = (xa[fi].x + xa[fi].y) + (xa[fi].z + xa[fi].w)
                 + (xc[fi].x + xc[fi].y) + (xc[fi].z + xc[fi].w);
        float qv = (xa[fi].x * xa[fi].x + xa[fi].y * xa[fi].y)
                 + (xa[fi].z * xa[fi].z + xa[fi].w * xa[fi].w)
                 + (xc[fi].x * xc[fi].x + xc[fi].y * xc[fi].y)
                 + (xc[fi].z * xc[fi].z + xc[fi].w * xc[fi].w);
        #pragma unroll
        for (int off = 32; off >= 1; off >>= 1) {
            sv += __shfl_xor(sv, off);
            qv += __shfl_xor(qv, off);
        }
        if (lane == 0) { fsum[wid * 16 + fi] = sv; fsq[wid * 16 + fi] = qv; }
        accS += (double)sv;            // wave-uniform
        accQ += (double)qv;
    }
    if (lane == 0) { wS[wid] = accS; wQ[wid] = accQ; }
    __syncthreads();
    if (tid == 0) {
        double S = wS[0] + wS[1] + wS[2] + wS[3];
        double Q = wQ[0] + wQ[1] + wQ[2] + wQ[3];
        __hip_atomic_store((u64*)&segS[bx], __double_as_longlong(S),
                           __ATOMIC_RELEASE, __HIP_MEMORY_SCOPE_AGENT);
        __hip_atomic_store((u64*)&segQ[bx], __double_as_longlong(Q),
                           __ATOMIC_RELEASE, __HIP_MEMORY_SCOPE_AGENT);
    }

    cg::this_grid().sync();

    // ---- phase B (wave 0): exclusive prefix + intra-block scan -----------
    if (wid == 0) {
        double es = 0.0, eq = 0.0;
        for (int base = 0; base < s; base += 64) {
            const int j = base + lane;
            double a = 0.0, q2 = 0.0;
            if (j < s) {
                a  = __longlong_as_double(__hip_atomic_load((u64*)&segS[b * SEGS + j],
                        __ATOMIC_ACQUIRE, __HIP_MEMORY_SCOPE_AGENT));
                q2 = __longlong_as_double(__hip_atomic_load((u64*)&segQ[b * SEGS + j],
                        __ATOMIC_ACQUIRE, __HIP_MEMORY_SCOPE_AGENT));
            }
            es += a; eq += q2;
        }
        #pragma unroll
        for (int off = 32; off >= 1; off >>= 1) {
            es += __shfl_xor(es, off);
            eq += __shfl_xor(eq, off);
        }
        // inclusive scan over the block's 64 per-frame sums (lane = frame)
        double sc = (double)fsum[lane], qc = (double)fsq[lane];
        #pragma unroll
        for (int off = 1; off < 64; off <<= 1) {
            double s2 = __shfl_up(sc, off);
            double q2 = __shfl_up(qc, off);
            if (lane >= off) { sc += s2; qc += q2; }
        }
        sc += es; qc += eq;
        const double cnt = (double)(s * FPB + lane + 1) * (double)HDIM;
        const double m   = sc / cnt;
        const double var = qc / cnt - m * m;
        meanS[lane] = (float)m;
        istdS[lane] = (float)(1.0 / sqrt(var + 1e-8));
    }
    __syncthreads();

    // ---- phase C: normalize straight from registers, NT stores ----------
    f32x4* o4 = (f32x4*)out + rowBase;
    #pragma unroll
    for (int fi = 0; fi < 16; ++fi) {
        const float m = meanS[wid * 16 + fi];
        const float r = istdS[wid * 16 + fi];
        f32x4 o0, o1;
        o0.x = g0.x * ((xa[fi].x - m) * r) + be0.x;
        o0.y = g0.y * ((xa[fi].y - m) * r) + be0.y;
        o0.z = g0.z * ((xa[fi].z - m) * r) + be0.z;
        o0.w = g0.w * ((xa[fi].w - m) * r) + be0.w;
        o1.x = g1.x * ((xc[fi].x - m) * r) + be1.x;
        o1.y = g1.y * ((xc[fi].y - m) * r) + be1.y;
        o1.z = g1.z * ((xc[fi].z - m) * r) + be1.z;
        o1.w = g1.w * ((xc[fi].w - m) * r) + be1.w;
        __builtin_nontemporal_store(o0, o4 + (size_t)fi * F4H + lane);
        __builtin_nontemporal_store(o1, o4 + (size_t)fi * F4H + 64 + lane);
    }
}

// ===================== fallback: proven 4-kernel pipeline ================
__global__ __launch_bounds__(256) void k_seg_sums(
    const float* __restrict__ in, float* __restrict__ ssum,
    float* __restrict__ ssq, double* __restrict__ segS,
    double* __restrict__ segQ, int K, int segsPerBatch)
{
    const int lane = threadIdx.x & 63;
    const int wid  = threadIdx.x >> 6;
    const int segGlobal = blockIdx.x;
    const int b   = segGlobal / segsPerBatch;
    const int seg = segGlobal % segsPerBatch;
    const int k0  = seg * SEG;

    double accS = 0.0, accQ = 0.0;
    #pragma unroll 4
    for (int i = 0; i < SEG / 4; ++i) {
        const int fk = k0 + wid * (SEG / 4) + i;
        if (fk < K) {
            const float4* p = (const float4*)in + ((size_t)b * K + fk) * F4H;
            float4 a = p[lane];
            float4 c = p[lane + 64];
            float s = (a.x + a.y) + (a.z + a.w) + (c.x + c.y) + (c.z + c.w);
            float q = (a.x * a.x + a.y * a.y) + (a.z * a.z + a.w * a.w)
                    + (c.x * c.x + c.y * c.y) + (c.z * c.z + c.w * c.w);
            #pragma unroll
            for (int off = 32; off >= 1; off >>= 1) {
                s += __shfl_xor(s, off);
                q += __shfl_xor(q, off);
            }
            if (lane == 0) {
                ssum[(size_t)b * K + fk] = s;
                ssq[(size_t)b * K + fk]  = q;
            }
            accS += (double)s;
            accQ += (double)q;
        }
    }
    __shared__ double wS[4], wQ[4];
    if (lane == 0) { wS[wid] = accS; wQ[wid] = accQ; }
    __syncthreads();
    if (threadIdx.x == 0) {
        segS[segGlobal] = wS[0] + wS[1] + wS[2] + wS[3];
        segQ[segGlobal] = wQ[0] + wQ[1] + wQ[2] + wQ[3];
    }
}

__global__ __launch_bounds__(512) void k_seg_scan(
    const double* __restrict__ segS, const double* __restrict__ segQ,
    double* __restrict__ offS, double* __restrict__ offQ, int segsPerBatch)
{
    const int lane = threadIdx.x & 63;
    const int b = threadIdx.x >> 6;
    if (b >= BATCHES) return;

    double carryS = 0.0, carryQ = 0.0;
    for (int base = 0; base < segsPerBatch; base += 64) {
        const int sidx = base + lane;
        const bool v = sidx < segsPerBatch;
        double s = v ? segS[(size_t)b * segsPerBatch + sidx] : 0.0;
        double q = v ? segQ[(size_t)b * segsPerBatch + sidx] : 0.0;
        const double sIn = s, qIn = q;
        #pragma unroll
        for (int off = 1; off < 64; off <<= 1) {
            double s2 = __shfl_up(s, off);
            double q2 = __shfl_up(q, off);
            if (lane >= off) { s += s2; q += q2; }
        }
        if (v) {
            offS[(size_t)b * segsPerBatch + sidx] = carryS + s - sIn;
            offQ[(size_t)b * segsPerBatch + sidx] = carryQ + q - qIn;
        }
        carryS += __shfl(s, 63);
        carryQ += __shfl(q, 63);
    }
}

__global__ __launch_bounds__(256) void k_frame_stats(
    const float* __restrict__ ssum, const float* __restrict__ ssq,
    const double* __restrict__ offS, const double* __restrict__ offQ,
    float* __restrict__ mean, float* __restrict__ istd,
    int K, int segsPerBatch)
{
    const int lane = threadIdx.x & 63;
    const int segGlobal = blockIdx.x * 4 + (threadIdx.x >> 6);
    if (segGlobal >= BATCHES * segsPerBatch) return;
    const int b   = segGlobal / segsPerBatch;
    const int seg = segGlobal % segsPerBatch;
    const int k   = seg * SEG + lane;

    double s = 0.0, q = 0.0;
    if (k < K) {
        s = (double)ssum[(size_t)b * K + k];
        q = (double)ssq[(size_t)b * K + k];
    }
    #pragma unroll
    for (int off = 1; off < 64; off <<= 1) {
        double s2 = __shfl_up(s, off);
        double q2 = __shfl_up(q, off);
        if (lane >= off) { s += s2; q += q2; }
    }
    if (k < K) {
        s += offS[segGlobal];
        q += offQ[segGlobal];
        const double cnt = (double)(k + 1) * (double)HDIM;
        const double m = s / cnt;
        const double var = q / cnt - m * m;
        mean[(size_t)b * K + k] = (float)m;
        istd[(size_t)b * K + k] = (float)(1.0 / sqrt(var + 1e-8));
    }
}

__global__ __launch_bounds__(256) void k_normalize(
    const float* __restrict__ in, const float* __restrict__ gamma,
    const float* __restrict__ beta, const float* __restrict__ mean,
    const float* __restrict__ istd, float* __restrict__ out, int nframes)
{
    const int t = threadIdx.x;
    const int frame = blockIdx.x * 2 + (t >> 7);
    const int c = t & (F4H - 1);
    if (frame >= nframes) return;

    const float m = mean[frame];
    const float r = istd[frame];
    const float4 g  = ((const float4*)gamma)[c];
    const float4 be = ((const float4*)beta)[c];
    const float4 x  = ((const float4*)in)[(size_t)frame * F4H + c];

    f32x4 o;
    o.x = g.x * ((x.x - m) * r) + be.x;
    o.y = g.y * ((x.y - m) * r) + be.y;
    o.z = g.z * ((x.z - m) * r) + be.z;
    o.w = g.w * ((x.w - m) * r) + be.w;
    __builtin_nontemporal_store(o, (f32x4*)out + (size_t)frame * F4H + c);
}

// =========================== host launcher ===============================
extern "C" void kernel_launch(void* const* d_in, const int* in_sizes, int n_in,
                              void* d_out, int out_size, void* d_ws, size_t ws_size,
                              hipStream_t stream)
{
    const float* in    = (const float*)d_in[0];
    const float* gamma = (const float*)d_in[1];
    const float* beta  = (const float*)d_in[2];
    float* out = (float*)d_out;

    const int H  = in_sizes[1];
    const int BK = in_sizes[0] / H;
    const int K  = BK / BATCHES;
    (void)n_in; (void)out_size; (void)ws_size;

    // ws: segS/segQ f64 [NBLK] (coop), then fallback arrays
    double* segS = (double*)d_ws;
    double* segQ = segS + NBLK;
    float* ssum = (float*)(segQ + NBLK);
    float* ssq  = ssum + BK;
    float* mean = ssq + BK;
    float* istd = mean + BK;
    double* fsegS = (double*)(istd + BK);
    double* fsegQ = fsegS + BATCHES * ((K + SEG - 1) / SEG);
    double* offS  = fsegQ + BATCHES * ((K + SEG - 1) / SEG);
    double* offQ  = offS  + BATCHES * ((K + SEG - 1) / SEG);

    // geometry + co-residency check for the cooperative path (deterministic
    // per device: same inputs -> same path every call)
    bool coop = (H == HDIM) && (K == KLEN) && (in_sizes[0] == BATCHES * KLEN * HDIM);
    if (coop) {
        int dev = 0, nb = 0, cus = 0;
        if (hipGetDevice(&dev) != hipSuccess) coop = false;
        if (coop && hipOccupancyMaxActiveBlocksPerMultiprocessor(
                        &nb, (const void*)cln_coop, 256, 0) != hipSuccess) coop = false;
        if (coop && hipDeviceGetAttribute(&cus, hipDeviceAttributeMultiprocessorCount,
                                          dev) != hipSuccess) coop = false;
        if (coop && (long)nb * cus < NBLK) coop = false;
    }

    if (coop) {
        void* args[] = {(void*)&in, (void*)&gamma, (void*)&beta,
                        (void*)&out, (void*)&segS, (void*)&segQ};
        hipLaunchCooperativeKernel((const void*)cln_coop, dim3(NBLK), dim3(256),
                                   args, 0, stream);
    } else {
        const int segsPerBatch = (K + SEG - 1) / SEG;
        const int NSEG = BATCHES * segsPerBatch;
        k_seg_sums<<<dim3(NSEG), dim3(256), 0, stream>>>(
            in, ssum, ssq, fsegS, fsegQ, K, segsPerBatch);
        k_seg_scan<<<dim3(1), dim3(512), 0, stream>>>(
            fsegS, fsegQ, offS, offQ, segsPerBatch);
        k_frame_stats<<<dim3((NSEG + 3) / 4), dim3(256), 0, stream>>>(
            ssum, ssq, offS, offQ, mean, istd, K, segsPerBatch);
        k_normalize<<<dim3((BK + 1) / 2), dim3(256), 0, stream>>>(
            in, gamma, beta, mean, istd, out, BK);
    }
}

// Round 7
// 67.125 us; speedup vs baseline: 1.0292x; 1.0282x over previous
//
#include <hip/hip_runtime.h>
#include <math.h>

// CumulativeLayerNorm [B=8, K=8000, H=512] f32.
// out[b,k,h] = gamma[h]*(x[b,k,h]-mean[b,k])*rsqrt(var[b,k]+1e-8)+beta[h],
// mean/var over prefix inputs[b,:k+1,:].
//
// 2-kernel pipeline (scan + stats folded into the normalize kernel):
//  k1: per-frame sum/sumsq (f32) + per-segment f64 aggregate  [reads 131 MB]
//  k2: per block (one 64-frame segment):
//        wave0: exclusive prefix over own batch's predecessor aggregates
//               (<=124 f64 pairs, L2-resident) + 64-lane shuffle scan of
//               own frame sums -> mean/istd in LDS        [~2 us preamble]
//        all waves: normalize 16 frames each, NT stores   [reads 131 MB,
//                                                          writes 131 MB]
// NT output stores bypass caches -> input stays L3-resident for k2 / next
// replay's k1.

#define HDIM 512
#define F4H (HDIM / 4)     // 128
#define SEG 64             // frames per segment/block
#define BATCHES 8

typedef float f32x4 __attribute__((ext_vector_type(4)));

// ------------- Kernel 1: per-frame sums + segment aggregates ------------
__global__ __launch_bounds__(256) void k_seg_sums(
    const float* __restrict__ in, float* __restrict__ ssum,
    float* __restrict__ ssq, double* __restrict__ segS,
    double* __restrict__ segQ, int K, int segsPerBatch)
{
    const int lane = threadIdx.x & 63;
    const int wid  = threadIdx.x >> 6;
    const int segGlobal = blockIdx.x;                 // b*segsPerBatch + seg
    const int b   = segGlobal / segsPerBatch;
    const int seg = segGlobal % segsPerBatch;
    const int k0  = seg * SEG;

    double accS = 0.0, accQ = 0.0;
    #pragma unroll 4
    for (int i = 0; i < SEG / 4; ++i) {               // 16 frames per wave
        const int fk = k0 + wid * (SEG / 4) + i;
        if (fk < K) {
            const float4* p = (const float4*)in + ((size_t)b * K + fk) * F4H;
            float4 a = p[lane];
            float4 c = p[lane + 64];
            float s = (a.x + a.y) + (a.z + a.w) + (c.x + c.y) + (c.z + c.w);
            float q = (a.x * a.x + a.y * a.y) + (a.z * a.z + a.w * a.w)
                    + (c.x * c.x + c.y * c.y) + (c.z * c.z + c.w * c.w);
            #pragma unroll
            for (int off = 32; off >= 1; off >>= 1) {
                s += __shfl_xor(s, off);
                q += __shfl_xor(q, off);
            }
            if (lane == 0) {
                ssum[(size_t)b * K + fk] = s;
                ssq[(size_t)b * K + fk]  = q;
            }
            accS += (double)s;                        // wave-uniform
            accQ += (double)q;
        }
    }
    __shared__ double wS[4], wQ[4];
    if (lane == 0) { wS[wid] = accS; wQ[wid] = accQ; }
    __syncthreads();
    if (threadIdx.x == 0) {
        segS[segGlobal] = wS[0] + wS[1] + wS[2] + wS[3];
        segQ[segGlobal] = wQ[0] + wQ[1] + wQ[2] + wQ[3];
    }
}

// ------------- Kernel 2: prefix + stats + normalize, fused ---------------
__global__ __launch_bounds__(256) void k_norm_fused(
    const float* __restrict__ in, const float* __restrict__ gamma,
    const float* __restrict__ beta, const float* __restrict__ ssum,
    const float* __restrict__ ssq, const double* __restrict__ segS,
    const double* __restrict__ segQ, float* __restrict__ out,
    int K, int segsPerBatch)
{
    __shared__ float meanS[SEG], istdS[SEG];

    const int tid  = threadIdx.x;
    const int lane = tid & 63;
    const int wid  = tid >> 6;
    const int segGlobal = blockIdx.x;
    const int b = segGlobal / segsPerBatch;
    const int s = segGlobal % segsPerBatch;
    const int k0 = s * SEG;

    // gamma/beta for this lane's columns (overlaps the wave0 preamble)
    const f32x4 g0  = ((const f32x4*)gamma)[lane];
    const f32x4 g1  = ((const f32x4*)gamma)[lane + 64];
    const f32x4 be0 = ((const f32x4*)beta)[lane];
    const f32x4 be1 = ((const f32x4*)beta)[lane + 64];

    // ---- preamble (wave 0): exclusive prefix + intra-segment scan -------
    if (wid == 0) {
        double es = 0.0, eq = 0.0;
        for (int base = 0; base < s; base += 64) {    // <=2 rounds (s<=124)
            const int j = base + lane;
            if (j < s) {
                es += segS[(size_t)b * segsPerBatch + j];
                eq += segQ[(size_t)b * segsPerBatch + j];
            }
        }
        #pragma unroll
        for (int off = 32; off >= 1; off >>= 1) {
            es += __shfl_xor(es, off);
            eq += __shfl_xor(eq, off);
        }
        // inclusive scan over this segment's 64 per-frame sums (lane=frame)
        const int k = k0 + lane;
        double sc = 0.0, qc = 0.0;
        if (k < K) {
            sc = (double)ssum[(size_t)b * K + k];
            qc = (double)ssq[(size_t)b * K + k];
        }
        #pragma unroll
        for (int off = 1; off < 64; off <<= 1) {
            double s2 = __shfl_up(sc, off);
            double q2 = __shfl_up(qc, off);
            if (lane >= off) { sc += s2; qc += q2; }
        }
        sc += es; qc += eq;
        if (k < K) {
            const double cnt = (double)(k + 1) * (double)HDIM;
            const double m   = sc / cnt;
            const double var = qc / cnt - m * m;
            meanS[lane] = (float)m;
            istdS[lane] = (float)(1.0 / sqrt(var + 1e-8));
        }
    }
    __syncthreads();

    // ---- normalize: each wave streams 16 frames, NT stores --------------
    #pragma unroll 4
    for (int i = 0; i < SEG / 4; ++i) {
        const int fi = wid * (SEG / 4) + i;
        const int k = k0 + fi;
        if (k < K) {
            const f32x4* p = (const f32x4*)in + ((size_t)b * K + k) * F4H;
            const f32x4 a = p[lane];
            const f32x4 c = p[lane + 64];
            const float m = meanS[fi];
            const float r = istdS[fi];
            f32x4 o0, o1;
            o0.x = g0.x * ((a.x - m) * r) + be0.x;
            o0.y = g0.y * ((a.y - m) * r) + be0.y;
            o0.z = g0.z * ((a.z - m) * r) + be0.z;
            o0.w = g0.w * ((a.w - m) * r) + be0.w;
            o1.x = g1.x * ((c.x - m) * r) + be1.x;
            o1.y = g1.y * ((c.y - m) * r) + be1.y;
            o1.z = g1.z * ((c.z - m) * r) + be1.z;
            o1.w = g1.w * ((c.w - m) * r) + be1.w;
            f32x4* q = (f32x4*)out + ((size_t)b * K + k) * F4H;
            __builtin_nontemporal_store(o0, q + lane);
            __builtin_nontemporal_store(o1, q + lane + 64);
        }
    }
}

// =========================== host launcher ===============================
extern "C" void kernel_launch(void* const* d_in, const int* in_sizes, int n_in,
                              void* d_out, int out_size, void* d_ws, size_t ws_size,
                              hipStream_t stream)
{
    const float* in    = (const float*)d_in[0];
    const float* gamma = (const float*)d_in[1];
    const float* beta  = (const float*)d_in[2];
    float* out = (float*)d_out;

    const int H = in_sizes[1];                  // 512
    const int BK = in_sizes[0] / H;             // B*K
    const int K = BK / BATCHES;                 // 8000
    const int segsPerBatch = (K + SEG - 1) / SEG;   // 125
    const int NSEG = BATCHES * segsPerBatch;        // 1000
    (void)H; (void)n_in; (void)out_size; (void)ws_size;

    // ws layout: ssum/ssq f32 [BK] then segS/segQ f64 [NSEG]
    float* ssum = (float*)d_ws;
    float* ssq  = ssum + BK;
    double* segS = (double*)(ssq + BK);
    double* segQ = segS + NSEG;

    k_seg_sums<<<dim3(NSEG), dim3(256), 0, stream>>>(
        in, ssum, ssq, segS, segQ, K, segsPerBatch);
    k_norm_fused<<<dim3(NSEG), dim3(256), 0, stream>>>(
        in, gamma, beta, ssum, ssq, segS, segQ, out, K, segsPerBatch);
}